// Round 11
// baseline (8836.412 us; speedup 1.0000x reference)
//
#include <hip/hip_runtime.h>

// Problem constants
#define NB 8
#define NT 1024
#define ND 768     // = 12*64
#define NH 12
#define NU 64
#define BT (NB*NT)   // 8192
#define SCALE32 ((float)0.03608439182435161)  // fp32(768^-0.5)
#define EPS32 1e-7f

// ---------------------------------------------------------------------------
// numpy baseline-SIMD (SSE2, no FMA) einsum dot over 64 contiguous elements:
// 4 accumulators stride-4, separate mul/add (rounded each), reduce
// (r0+r2)+(r1+r3). __f*_rn blocks hipcc contraction. BITWISE-IDENTICAL to R9.
// ---------------------------------------------------------------------------
__device__ __forceinline__ float dot64_np(const float* a, const float* b)
{
    float r[4];
#pragma unroll
    for (int j = 0; j < 4; j++) r[j] = __fmul_rn(a[j], b[j]);
#pragma unroll
    for (int i = 1; i < 16; i++)
#pragma unroll
        for (int j = 0; j < 4; j++)
            r[j] = __fadd_rn(r[j], __fmul_rn(a[i * 4 + j], b[i * 4 + j]));
    return __fadd_rn(__fadd_rn(r[0], r[2]), __fadd_rn(r[1], r[3]));
}

// ---------------------------------------------------------------------------
// Mask decode with byte/int32 layout sniff (mask is all-ones in practice).
// ---------------------------------------------------------------------------
__global__ __launch_bounds__(256) void mask_k(
    const unsigned char* __restrict__ mb, float* __restrict__ mf)
{
    __shared__ int cntOff, cntAll;
    if (threadIdx.x == 0) { cntOff = 0; cntAll = 0; }
    __syncthreads();
    int lo = 0, la = 0;
    for (int i = threadIdx.x; i < BT; i += 256)
        if (mb[i] != 0) { la++; if ((i & 3) != 0) lo++; }
    atomicAdd(&cntOff, lo);
    atomicAdd(&cntAll, la);
    __syncthreads();
    const bool int32mode = (cntOff == 0) && (cntAll != 0);
    if (int32mode) {
        const int* mi = (const int*)mb;
        for (int i = threadIdx.x; i < BT; i += 256)
            mf[i] = (mi[i] != 0) ? 1.f : 0.f;
    } else {
        for (int i = threadIdx.x; i < BT; i += 256)
            mf[i] = (mb[i] != 0) ? 1.f : 0.f;
    }
}

// ---------------------------------------------------------------------------
// OpenBLAS-mimic sgemm: C = A[8192x768] @ W[768x768] (+R elementwise after).
// kc=384 panel split preserved bitwise (unchanged from R10). grid (128,12).
// ---------------------------------------------------------------------------
__global__ __launch_bounds__(256) void gemmseq(
    const float* __restrict__ A, const float* __restrict__ W,
    const float* __restrict__ R, float* __restrict__ C)
{
    __shared__ float sA[64][68];   // [k][m], transposed, pad 68 (16B-aligned rows)
    __shared__ float sB[64][68];   // [k][n]

    const int t = threadIdx.x;
    const int mbase = blockIdx.x * 64;
    const int nbase = blockIdx.y * 64;
    const int m0 = (t >> 4) * 4;
    const int n0 = (t & 15) * 4;

    float acc[4][4], accA[4][4];
#pragma unroll
    for (int i = 0; i < 4; i++)
#pragma unroll
        for (int j = 0; j < 4; j++) { acc[i][j] = 0.f; accA[i][j] = 0.f; }

    for (int k0 = 0; k0 < 768; k0 += 64) {
        __syncthreads();
#pragma unroll
        for (int i = 0; i < 4; i++) {
            const int idx = t + i * 256;          // 0..1023
            const int mr = idx >> 4;              // 0..63
            const int k4 = (idx & 15) * 4;        // 0..60
            const float4 a4 = *(const float4*)&A[(size_t)(mbase + mr) * 768 + k0 + k4];
            sA[k4 + 0][mr] = a4.x;
            sA[k4 + 1][mr] = a4.y;
            sA[k4 + 2][mr] = a4.z;
            sA[k4 + 3][mr] = a4.w;
            *(float4*)&sB[mr][k4] =
                *(const float4*)&W[(size_t)(k0 + mr) * 768 + nbase + k4];
        }
        __syncthreads();

        for (int kk = 0; kk < 64; kk++) {
            float av[4], bv[4];
            *(float4*)&av[0] = *(const float4*)&sA[kk][m0];
            *(float4*)&bv[0] = *(const float4*)&sB[kk][n0];
#pragma unroll
            for (int i = 0; i < 4; i++)
#pragma unroll
                for (int j = 0; j < 4; j++)
                    acc[i][j] = fmaf(av[i], bv[j], acc[i][j]);
        }

        if (k0 + 64 == 384) {   // end of first kc panel (OpenBLAS kc=384)
#pragma unroll
            for (int i = 0; i < 4; i++)
#pragma unroll
                for (int j = 0; j < 4; j++) {
                    accA[i][j] = acc[i][j];
                    acc[i][j] = 0.f;
                }
        }
    }

#pragma unroll
    for (int i = 0; i < 4; i++)
#pragma unroll
        for (int j = 0; j < 4; j++) {
            const size_t idx = (size_t)(mbase + m0 + i) * 768 + nbase + n0 + j;
            float o = __fadd_rn(accA[i][j], acc[i][j]);  // C = panel0 + panel1
            if (R) o = __fadd_rn(o, R[idx]);             // np: out = tmp + x
            C[idx] = o;
        }
}

// ---------------------------------------------------------------------------
// FUSED denominator + attention. One WAVE per (row,head); block = 4 waves =
// 4 consecutive rows of one bh, sharing LDS K staging.
//
// Lane l <-> numpy chain (C=l>>3, j=l&7): holds the 16 scores
// s = C*128 + 8*i + j (i=0..15), each computed with the bitwise dot64_np.
// D reduction: ascending-i chain (= numpy b8[j] ascending-s), then xor-
// butterfly 1,2,4 (j-tree) and 8,16,32 (C-tree) — add shapes identical to
// numpy's pairwise tree; fp add commutativity makes per-lane operand swaps
// bitwise-neutral. p = sc/(D+eps) per slot. Axpy: lane u owns o[u], chains
// ascending s with p broadcast via shfl and coalesced v dword loads.
// grid 24576 x 256.
// ---------------------------------------------------------------------------
__global__ __launch_bounds__(256) void attn_fused(
    const float* __restrict__ K, const float* __restrict__ V,
    const float* __restrict__ MF, float* __restrict__ QA)
{
    __shared__ float sk[64][65];   // K rows for current slot; stride 65 -> 2-way max

    const int tid = threadIdx.x;
    const int wave = tid >> 6, lane = tid & 63;
    const int blk = blockIdx.x;
    const int bh = blk >> 8;              // 256 blocks per bh
    const int row = (blk & 255) * 4 + wave;
    const int b = bh / NH, h = bh % NH;
    const int C = lane >> 3, j = lane & 7;

    const float* Kb = K + ((size_t)b * NT) * ND + h * 64;
    const float* Vb = V + ((size_t)b * NT) * ND + h * 64;
    const float* MFb = MF + b * NT;
    float* QArow = QA + ((size_t)(b * NT + row)) * ND + h * 64;

    // q row (wave-uniform content, replicated per lane; same-address loads)
    float qr[64];
#pragma unroll
    for (int i = 0; i < 16; i++)
        *(float4*)&qr[i * 4] = ((const float4*)QArow)[i];

    const float mq = MFb[row];

    float sc[16];

#pragma unroll
    for (int i = 0; i < 16; i++) {        // slot loop: 64 s-rows per slot
        __syncthreads();
#pragma unroll
        for (int it = 0; it < 4; it++) {  // stage 64 rows x 16 float4
            const int idx = tid + it * 256;
            const int r = idx >> 4;               // LDS row 0..63
            const int c4 = (idx & 15) * 4;
            const int s = (r >> 3) * 128 + 8 * i + (r & 7);
            *(float4*)&sk[r][c4] = *(const float4*)&Kb[(size_t)s * ND + c4];
        }
        __syncthreads();

        const int s_l = C * 128 + 8 * i + j;
        const float dt = dot64_np(qr, &sk[lane][0]);  // bitwise R10 chain
        float v = __fmul_rn(dt, SCALE32);
        v = __fmul_rn(v, MFb[s_l]);
        v = __fmul_rn(v, mq);
        sc[i] = v;
    }

    // numpy pairwise reduction to D (bitwise: b8 chain + Bi tree + D tree)
    float b8 = sc[0];
#pragma unroll
    for (int i = 1; i < 16; i++) b8 = __fadd_rn(b8, sc[i]);
    float tr = b8;
    tr = __fadd_rn(tr, __shfl_xor(tr, 1, 64));
    tr = __fadd_rn(tr, __shfl_xor(tr, 2, 64));
    tr = __fadd_rn(tr, __shfl_xor(tr, 4, 64));   // Bi[C]
    tr = __fadd_rn(tr, __shfl_xor(tr, 8, 64));
    tr = __fadd_rn(tr, __shfl_xor(tr, 16, 64));
    tr = __fadd_rn(tr, __shfl_xor(tr, 32, 64));  // D
    const float De = __fadd_rn(tr, EPS32);       // np: sum + eps

    // p = sc / De (same value as R10's per-s division)
#pragma unroll
    for (int i = 0; i < 16; i++) sc[i] = __fdiv_rn(sc[i], De);

    // axpy: lane u owns o; ascending s = C'*128 + 8*i + j'; p from lane C'*8+j'
    float o = 0.f;
    for (int Cp = 0; Cp < 8; Cp++) {
#pragma unroll
        for (int i = 0; i < 16; i++) {
#pragma unroll
            for (int jp = 0; jp < 8; jp++) {
                const int s = Cp * 128 + 8 * i + jp;
                const float p = __shfl(sc[i], Cp * 8 + jp, 64);
                const float vv = Vb[(size_t)s * ND + lane];   // coalesced
                o = __fadd_rn(o, __fmul_rn(p, vv));           // np SSE2 axpy
            }
        }
    }

    QArow[lane] = o;
}

// ---------------------------------------------------------------------------
// Row norm, numpy-faithful pairwise mean via ONE WAVE per row (bitwise R10).
// grid 2048 x 256 (4 waves/block).
// ---------------------------------------------------------------------------
__global__ __launch_bounds__(256) void rownorm_np(
    float* __restrict__ Y, const float* __restrict__ gamma,
    const float* __restrict__ beta)
{
    const int wave = threadIdx.x >> 6, lane = threadIdx.x & 63;
    const int row = blockIdx.x * 4 + wave;
    float* yr = Y + (size_t)row * ND;
    const int c = lane >> 3, j = lane & 7;

    const float* a = yr + c * 96;
    float r = a[j];
#pragma unroll
    for (int i = 1; i < 12; i++) r = __fadd_rn(r, a[i * 8 + j]);

    r = __fadd_rn(r, __shfl_xor(r, 1, 64));
    r = __fadd_rn(r, __shfl_xor(r, 2, 64));
    r = __fadd_rn(r, __shfl_xor(r, 4, 64));
    r = __fadd_rn(r, __shfl_xor(r, 8, 64));
    r = __fadd_rn(r, __shfl_xor(r, 16, 64));
    r = __fadd_rn(r, __shfl_xor(r, 32, 64));

    const float m = __fdiv_rn(r, 768.0f);
    const float mpe = __fadd_rn(m, EPS32);

#pragma unroll
    for (int i = 0; i < 12; i++) {
        const int idx = i * 64 + lane;
        const float v = yr[idx];
        float o = __fsub_rn(v, m);
        o = __fmul_rn(gamma[idx], o);
        o = __fdiv_rn(o, mpe);
        o = __fadd_rn(o, beta[idx]);
        yr[idx] = o;
    }
}

// ---------------------------------------------------------------------------
extern "C" void kernel_launch(void* const* d_in, const int* in_sizes, int n_in,
                              void* d_out, int out_size, void* d_ws, size_t ws_size,
                              hipStream_t stream)
{
    (void)in_sizes; (void)n_in; (void)out_size; (void)ws_size;
    const float* x     = (const float*)d_in[0];
    const unsigned char* maskb = (const unsigned char*)d_in[1];
    const float* wq    = (const float*)d_in[2];
    const float* wk    = (const float*)d_in[3];
    const float* wv    = (const float*)d_in[4];
    const float* wf    = (const float*)d_in[5];
    const float* gamma = (const float*)d_in[6];
    const float* beta  = (const float*)d_in[7];

    float* ws = (float*)d_ws;
    float* MF = ws;                             // 8192
    float* Q  = MF + BT;                        // 8192*768 (becomes A)
    float* K  = Q + (size_t)BT * ND;            // 8192*768
    float* V  = K + (size_t)BT * ND;            // 8192*768
    float* Y  = (float*)d_out;                  // total ws: 75.5 MB

    mask_k<<<1, 256, 0, stream>>>(maskb, MF);
    gemmseq<<<dim3(128, 12), 256, 0, stream>>>(x, wq, nullptr, Q);
    gemmseq<<<dim3(128, 12), 256, 0, stream>>>(x, wk, nullptr, K);
    gemmseq<<<dim3(128, 12), 256, 0, stream>>>(x, wv, nullptr, V);
    attn_fused<<<24576, 256, 0, stream>>>(K, V, MF, Q);   // Q -> A in place
    gemmseq<<<dim3(128, 12), 256, 0, stream>>>(Q, wf, x, Y);
    rownorm_np<<<2048, 256, 0, stream>>>(Y, gamma, beta);
}

// Round 12
// 3003.372 us; speedup vs baseline: 2.9422x; 2.9422x over previous
//
#include <hip/hip_runtime.h>

// Problem constants
#define NB 8
#define NT 1024
#define ND 768     // = 12*64
#define NH 12
#define NU 64
#define BT (NB*NT)   // 8192
#define SCALE32 ((float)0.03608439182435161)  // fp32(768^-0.5)
#define EPS32 1e-7f

// ---------------------------------------------------------------------------
// Mask decode with byte/int32 layout sniff (mask is all-ones in practice).
// ---------------------------------------------------------------------------
__global__ __launch_bounds__(256) void mask_k(
    const unsigned char* __restrict__ mb, float* __restrict__ mf)
{
    __shared__ int cntOff, cntAll;
    if (threadIdx.x == 0) { cntOff = 0; cntAll = 0; }
    __syncthreads();
    int lo = 0, la = 0;
    for (int i = threadIdx.x; i < BT; i += 256)
        if (mb[i] != 0) { la++; if ((i & 3) != 0) lo++; }
    atomicAdd(&cntOff, lo);
    atomicAdd(&cntAll, la);
    __syncthreads();
    const bool int32mode = (cntOff == 0) && (cntAll != 0);
    if (int32mode) {
        const int* mi = (const int*)mb;
        for (int i = threadIdx.x; i < BT; i += 256)
            mf[i] = (mi[i] != 0) ? 1.f : 0.f;
    } else {
        for (int i = threadIdx.x; i < BT; i += 256)
            mf[i] = (mb[i] != 0) ? 1.f : 0.f;
    }
}

// ---------------------------------------------------------------------------
// OpenBLAS-mimic sgemm: C = A[8192x768] @ W[768x768] (+R elementwise after).
// kc=384 panel split preserved bitwise (unchanged from R10). grid (128,12).
// ---------------------------------------------------------------------------
__global__ __launch_bounds__(256) void gemmseq(
    const float* __restrict__ A, const float* __restrict__ W,
    const float* __restrict__ R, float* __restrict__ C)
{
    __shared__ float sA[64][68];   // [k][m], transposed, pad 68 (16B-aligned rows)
    __shared__ float sB[64][68];   // [k][n]

    const int t = threadIdx.x;
    const int mbase = blockIdx.x * 64;
    const int nbase = blockIdx.y * 64;
    const int m0 = (t >> 4) * 4;
    const int n0 = (t & 15) * 4;

    float acc[4][4], accA[4][4];
#pragma unroll
    for (int i = 0; i < 4; i++)
#pragma unroll
        for (int j = 0; j < 4; j++) { acc[i][j] = 0.f; accA[i][j] = 0.f; }

    for (int k0 = 0; k0 < 768; k0 += 64) {
        __syncthreads();
#pragma unroll
        for (int i = 0; i < 4; i++) {
            const int idx = t + i * 256;          // 0..1023
            const int mr = idx >> 4;              // 0..63
            const int k4 = (idx & 15) * 4;        // 0..60
            const float4 a4 = *(const float4*)&A[(size_t)(mbase + mr) * 768 + k0 + k4];
            sA[k4 + 0][mr] = a4.x;
            sA[k4 + 1][mr] = a4.y;
            sA[k4 + 2][mr] = a4.z;
            sA[k4 + 3][mr] = a4.w;
            *(float4*)&sB[mr][k4] =
                *(const float4*)&W[(size_t)(k0 + mr) * 768 + nbase + k4];
        }
        __syncthreads();

        for (int kk = 0; kk < 64; kk++) {
            float av[4], bv[4];
            *(float4*)&av[0] = *(const float4*)&sA[kk][m0];
            *(float4*)&bv[0] = *(const float4*)&sB[kk][n0];
#pragma unroll
            for (int i = 0; i < 4; i++)
#pragma unroll
                for (int j = 0; j < 4; j++)
                    acc[i][j] = fmaf(av[i], bv[j], acc[i][j]);
        }

        if (k0 + 64 == 384) {   // end of first kc panel (OpenBLAS kc=384)
#pragma unroll
            for (int i = 0; i < 4; i++)
#pragma unroll
                for (int j = 0; j < 4; j++) {
                    accA[i][j] = acc[i][j];
                    acc[i][j] = 0.f;
                }
        }
    }

#pragma unroll
    for (int i = 0; i < 4; i++)
#pragma unroll
        for (int j = 0; j < 4; j++) {
            const size_t idx = (size_t)(mbase + m0 + i) * 768 + nbase + n0 + j;
            float o = __fadd_rn(accA[i][j], acc[i][j]);  // C = panel0 + panel1
            if (R) o = __fadd_rn(o, R[idx]);             // np: out = tmp + x
            C[idx] = o;
        }
}

// ---------------------------------------------------------------------------
// Denominator part 1: thread (row, C) computes numpy base-128 block Bi[C]
// with the bitwise-identical chains: sc_s = ((q.k)*scale)*mk*mq, b8[j]
// ascending chain, Bi tree. k streamed via same-address float4 VMEM loads
// (wave-uniform row C*128+i); dot inlined = dot64_np bitwise.
// grid 3072 x 256 (bh = blk>>5, C = (blk&31)>>2, rowGroup = blk&3).
// ---------------------------------------------------------------------------
__global__ __launch_bounds__(256) void denom_part(
    const float* __restrict__ Q, const float* __restrict__ K,
    const float* __restrict__ MF, float* __restrict__ BiP)
{
    const int blk = blockIdx.x;
    const int bh = blk >> 5;
    const int C = (blk & 31) >> 2;
    const int row = (blk & 3) * 256 + threadIdx.x;
    const int b = bh / NH, h = bh % NH;

    const float mq = MF[b * NT + row];

    float qr[64];
    const float4* qp = (const float4*)&Q[((size_t)(b * NT + row)) * ND + h * 64];
#pragma unroll
    for (int i = 0; i < 16; i++) *(float4*)&qr[i * 4] = qp[i];

    const float* Kb = &K[((size_t)b * NT) * ND + h * 64];
    const float* MFb = &MF[b * NT];

    float b8[8];
#pragma unroll 2
    for (int i = 0; i < 128; i++) {
        const int s = C * 128 + i;
        const float4* kp = (const float4*)(Kb + (size_t)s * ND);
        // inline dot64_np: 4 accumulators stride-4, mul+add, float4 steps
        float4 k4 = kp[0];
        float r0 = __fmul_rn(qr[0], k4.x);
        float r1 = __fmul_rn(qr[1], k4.y);
        float r2 = __fmul_rn(qr[2], k4.z);
        float r3 = __fmul_rn(qr[3], k4.w);
#pragma unroll
        for (int c = 1; c < 16; c++) {
            k4 = kp[c];
            r0 = __fadd_rn(r0, __fmul_rn(qr[c * 4 + 0], k4.x));
            r1 = __fadd_rn(r1, __fmul_rn(qr[c * 4 + 1], k4.y));
            r2 = __fadd_rn(r2, __fmul_rn(qr[c * 4 + 2], k4.z));
            r3 = __fadd_rn(r3, __fmul_rn(qr[c * 4 + 3], k4.w));
        }
        const float dt = __fadd_rn(__fadd_rn(r0, r2), __fadd_rn(r1, r3));
        float sc = __fmul_rn(dt, SCALE32);
        sc = __fmul_rn(sc, MFb[s]);
        sc = __fmul_rn(sc, mq);
        const int j = i & 7;
        if (i < 8) b8[j] = sc;
        else       b8[j] = __fadd_rn(b8[j], sc);
    }

    const float Bi = __fadd_rn(
        __fadd_rn(__fadd_rn(b8[0], b8[1]), __fadd_rn(b8[2], b8[3])),
        __fadd_rn(__fadd_rn(b8[4], b8[5]), __fadd_rn(b8[6], b8[7])));
    BiP[((size_t)bh * NT + row) * 8 + C] = Bi;
}

// ---------------------------------------------------------------------------
// Denominator part 2: D = numpy two-level tree over the 8 Bi blocks
// (bitwise-identical shape). grid 384 x 256.
// ---------------------------------------------------------------------------
__global__ __launch_bounds__(256) void denom_comb(
    const float* __restrict__ BiP, float* __restrict__ D)
{
    const int idx = blockIdx.x * 256 + threadIdx.x;   // bh*1024+row
    const float* p = BiP + (size_t)idx * 8;
    D[idx] = __fadd_rn(
        __fadd_rn(__fadd_rn(p[0], p[1]), __fadd_rn(p[2], p[3])),
        __fadd_rn(__fadd_rn(p[4], p[5]), __fadd_rn(p[6], p[7])));
}

// ---------------------------------------------------------------------------
// Attention out. One THREAD per row: q + o[64] in registers; k/v streamed
// via same-address float4 VMEM loads (wave-uniform rows -> one request);
// dot inlined bitwise = dot64_np; axpy mul+add ascending s (= R10 chains).
// unroll 2 lets iteration i+1 loads overlap iteration i VALU.
// Self-aliased QA. grid 384 x 256.
// ---------------------------------------------------------------------------
__global__ __launch_bounds__(256) void attn_np(
    const float* __restrict__ K, const float* __restrict__ V,
    const float* __restrict__ D, const float* __restrict__ MF,
    float* __restrict__ QA)   // in: Q, out: A (self-aliased per row)
{
    const int gid = blockIdx.x * 256 + threadIdx.x;
    const int bh = gid >> 10;
    const int row = gid & 1023;
    const int b = bh / NH, h = bh % NH;

    const float mq = MF[b * NT + row];
    const float De = __fadd_rn(D[(size_t)bh * NT + row], EPS32);  // np: sum+eps

    float qr[64];
    const float4* qp = (const float4*)&QA[((size_t)(b * NT + row)) * ND + h * 64];
#pragma unroll
    for (int i = 0; i < 16; i++) *(float4*)&qr[i * 4] = qp[i];

    float o[64];
#pragma unroll
    for (int j = 0; j < 64; j++) o[j] = 0.f;

    const float* Kb = &K[((size_t)b * NT) * ND + h * 64];
    const float* Vb = &V[((size_t)b * NT) * ND + h * 64];
    const float* MFb = &MF[b * NT];

#pragma unroll 2
    for (int s = 0; s < NT; s++) {
        const float4* kp = (const float4*)(Kb + (size_t)s * ND);
        const float4* vp = (const float4*)(Vb + (size_t)s * ND);
        // inline dot64_np (bitwise): 4 accs stride-4, mul+add, float4 steps
        float4 k4 = kp[0];
        float r0 = __fmul_rn(qr[0], k4.x);
        float r1 = __fmul_rn(qr[1], k4.y);
        float r2 = __fmul_rn(qr[2], k4.z);
        float r3 = __fmul_rn(qr[3], k4.w);
#pragma unroll
        for (int c = 1; c < 16; c++) {
            k4 = kp[c];
            r0 = __fadd_rn(r0, __fmul_rn(qr[c * 4 + 0], k4.x));
            r1 = __fadd_rn(r1, __fmul_rn(qr[c * 4 + 1], k4.y));
            r2 = __fadd_rn(r2, __fmul_rn(qr[c * 4 + 2], k4.z));
            r3 = __fadd_rn(r3, __fmul_rn(qr[c * 4 + 3], k4.w));
        }
        const float dt = __fadd_rn(__fadd_rn(r0, r2), __fadd_rn(r1, r3));
        float sc = __fmul_rn(dt, SCALE32);
        sc = __fmul_rn(sc, MFb[s]);
        sc = __fmul_rn(sc, mq);
        const float p = __fdiv_rn(sc, De);
        // axpy ascending u in float4 steps (chain per o[j] unchanged)
#pragma unroll
        for (int c = 0; c < 16; c++) {
            const float4 v4 = vp[c];
            o[c * 4 + 0] = __fadd_rn(o[c * 4 + 0], __fmul_rn(p, v4.x));
            o[c * 4 + 1] = __fadd_rn(o[c * 4 + 1], __fmul_rn(p, v4.y));
            o[c * 4 + 2] = __fadd_rn(o[c * 4 + 2], __fmul_rn(p, v4.z));
            o[c * 4 + 3] = __fadd_rn(o[c * 4 + 3], __fmul_rn(p, v4.w));
        }
    }

    float4* op = (float4*)&QA[((size_t)(b * NT + row)) * ND + h * 64];
#pragma unroll
    for (int i = 0; i < 16; i++) op[i] = *(float4*)&o[i * 4];
}

// ---------------------------------------------------------------------------
// Row norm, numpy-faithful pairwise mean via ONE WAVE per row (bitwise R10).
// grid 2048 x 256 (4 waves/block).
// ---------------------------------------------------------------------------
__global__ __launch_bounds__(256) void rownorm_np(
    float* __restrict__ Y, const float* __restrict__ gamma,
    const float* __restrict__ beta)
{
    const int wave = threadIdx.x >> 6, lane = threadIdx.x & 63;
    const int row = blockIdx.x * 4 + wave;
    float* yr = Y + (size_t)row * ND;
    const int c = lane >> 3, j = lane & 7;

    const float* a = yr + c * 96;
    float r = a[j];
#pragma unroll
    for (int i = 1; i < 12; i++) r = __fadd_rn(r, a[i * 8 + j]);

    r = __fadd_rn(r, __shfl_xor(r, 1, 64));
    r = __fadd_rn(r, __shfl_xor(r, 2, 64));
    r = __fadd_rn(r, __shfl_xor(r, 4, 64));
    r = __fadd_rn(r, __shfl_xor(r, 8, 64));
    r = __fadd_rn(r, __shfl_xor(r, 16, 64));
    r = __fadd_rn(r, __shfl_xor(r, 32, 64));

    const float m = __fdiv_rn(r, 768.0f);
    const float mpe = __fadd_rn(m, EPS32);

#pragma unroll
    for (int i = 0; i < 12; i++) {
        const int idx = i * 64 + lane;
        const float v = yr[idx];
        float o = __fsub_rn(v, m);
        o = __fmul_rn(gamma[idx], o);
        o = __fdiv_rn(o, mpe);
        o = __fadd_rn(o, beta[idx]);
        yr[idx] = o;
    }
}

// ---------------------------------------------------------------------------
extern "C" void kernel_launch(void* const* d_in, const int* in_sizes, int n_in,
                              void* d_out, int out_size, void* d_ws, size_t ws_size,
                              hipStream_t stream)
{
    (void)in_sizes; (void)n_in; (void)out_size; (void)ws_size;
    const float* x     = (const float*)d_in[0];
    const unsigned char* maskb = (const unsigned char*)d_in[1];
    const float* wq    = (const float*)d_in[2];
    const float* wk    = (const float*)d_in[3];
    const float* wv    = (const float*)d_in[4];
    const float* wf    = (const float*)d_in[5];
    const float* gamma = (const float*)d_in[6];
    const float* beta  = (const float*)d_in[7];

    float* ws = (float*)d_ws;
    float* MF  = ws;                            // 8192
    float* D   = MF + BT;                       // 96*1024
    float* BiP = D + (size_t)96 * NT;           // 96*1024*8 = 3.1 MB
    float* Q   = BiP + (size_t)96 * NT * 8;     // 8192*768 (becomes A)
    float* K   = Q + (size_t)BT * ND;           // 8192*768
    float* V   = K + (size_t)BT * ND;           // 8192*768
    float* Y   = (float*)d_out;                 // total ws: ~75.6 MB

    mask_k<<<1, 256, 0, stream>>>(maskb, MF);
    gemmseq<<<dim3(128, 12), 256, 0, stream>>>(x, wq, nullptr, Q);
    gemmseq<<<dim3(128, 12), 256, 0, stream>>>(x, wk, nullptr, K);
    gemmseq<<<dim3(128, 12), 256, 0, stream>>>(x, wv, nullptr, V);
    denom_part<<<3072, 256, 0, stream>>>(Q, K, MF, BiP);
    denom_comb<<<384, 256, 0, stream>>>(BiP, D);
    attn_np<<<384, 256, 0, stream>>>(K, V, D, MF, Q);  // Q -> A
    gemmseq<<<dim3(128, 12), 256, 0, stream>>>(Q, wf, x, Y);
    rownorm_np<<<2048, 256, 0, stream>>>(Y, gamma, beta);
}